// Round 13
// baseline (22227.728 us; speedup 1.0000x reference)
//
#include <hip/hip_runtime.h>
#include <math.h>

// Round 13 = round 11 BYTE-FOR-BYTE (best, 5401 us), with the
// amdgpu_waves_per_eu attribute REMOVED. Theory: the attribute's upper bound
// (8) made the backend target 8 waves/EU => 64-VGPR budget (the pin observed
// in every round), forcing ~1 GB/dispatch of scratch spill in the ~80-reg hot
// phases. Without the attribute the backend derives occupancy from static LDS
// (72 KB => 2 wg/CU => 4 waves/SIMD) => 128-VGPR budget, zero occupancy cost.
// Single-variable A/B on the best kernel.

#define YQ(s, q) ((s) * 128 + 4 * ((q) ^ ((s) & 7)))
#define KA_STR 68
#define QA_STR 72
#define QA_BASE 4420   // floats; byte offset 17680 (16B aligned)

__global__
__attribute__((amdgpu_flat_work_group_size(512, 512)))
void literal_kernel(const float* __restrict__ in0,
                    const float* __restrict__ emb,
                    const float* __restrict__ wk11, const float* __restrict__ wq11,
                    const float* __restrict__ wv11,
                    const float* __restrict__ wk12, const float* __restrict__ wq12,
                    const float* __restrict__ wv12,
                    const float* __restrict__ l1,
                    const float* __restrict__ wk21, const float* __restrict__ wq21,
                    const float* __restrict__ wv21,
                    const float* __restrict__ wk22, const float* __restrict__ wq22,
                    const float* __restrict__ wv22,
                    const float* __restrict__ l2,
                    const float* __restrict__ L3, const float* __restrict__ L4,
                    float* __restrict__ out)
{
    __shared__ __align__(16) float vsh[8320];   // v[i][t] stride 65; later y2 (YQ)
    __shared__ __align__(16) float R1[9028];    // kA[65][68]@0, qA[64][72]@4420;
                                                // att[s*128+i] overlay; scratch
    __shared__ __align__(16) float k64sh[128];  // k[:,64] / k2[:,64]; then u[h]
    __shared__ __align__(16) float q64sh[128];  // q[:,64] / q2[:,64]
    __shared__ float kq64sh[68];
    __shared__ __align__(16) float smr[68];
    __shared__ __align__(16) float attr[128];   // st1: att_a0[64][.] stash; st2: att2
    __shared__ float y4sh[128];

    const int tid  = threadIdx.x;
    const int lane = tid & 63;
    const int wu   = __builtin_amdgcn_readfirstlane(tid >> 6);   // wave 0..7
    const long b   = blockIdx.x;
    const float xr = in0[b * 64 + lane];

    float* kA = R1;
    float* qA = R1 + QA_BASE;

    const int h4 = (tid & 31) * 4;
    const int sb = tid >> 5;          // 0..15
    float4 acc1[4];
    #pragma unroll
    for (int si = 0; si < 4; ++si) acc1[si] = make_float4(0.f, 0.f, 0.f, 0.f);

    // =================== stage 1 ===================
    for (int a = 0; a < 2; ++a) {
        const float* wk = a ? wk12 : wk11;
        const float* wq = a ? wq12 : wq11;
        const float* wv = a ? wv12 : wv11;

        float kqa[8];
        #pragma unroll
        for (int m = 0; m < 8; ++m) kqa[m] = 0.f;
        float kq64acc = 0.f, kqr64acc = 0.f, corner = 0.f;   // wave-0 extras

        for (int p = 0; p < 2; ++p) {
            const int ip0 = p * 64 + wu * 8;
            // ---- projection pass p: rows ip0..ip0+7, lanes = column s/t ----
            float aK[8], aQ[8], aV[8];
            #pragma unroll
            for (int r = 0; r < 8; ++r) { aK[r] = aQ[r] = aV[r] = 0.f; }
            float acc64 = 0.f;                     // lane<8:K64 8..15:Q64 16..23:V64
            {
                const int ch = lane >> 3;
                const float* Wc = (ch == 0) ? wk : ((ch == 1) ? wq : wv);
                const float* wcrow = Wc + (ip0 + (lane & 7)) * 128;
                for (int jq = 0; jq < 32; ++jq) {
                    const float* erow = emb + (jq * 4) * 65;
                    float yv[4];
                    #pragma unroll
                    for (int u = 0; u < 4; ++u) yv[u] = erow[u * 65 + lane] * xr;
                    #pragma unroll
                    for (int r = 0; r < 8; ++r) {
                        const float* wkr = wk + (ip0 + r) * 128 + jq * 4;
                        const float* wqr = wq + (ip0 + r) * 128 + jq * 4;
                        const float* wvr = wv + (ip0 + r) * 128 + jq * 4;
                        #pragma unroll
                        for (int u = 0; u < 4; ++u) {
                            aK[r] = fmaf(wkr[u], yv[u], aK[r]);
                            aQ[r] = fmaf(wqr[u], yv[u], aQ[r]);
                            aV[r] = fmaf(wvr[u], yv[u], aV[r]);
                        }
                    }
                    if (lane < 24) {
                        float4 c0 = *(const float4*)&wcrow[jq * 4];
                        acc64 = fmaf(c0.x, erow[0 * 65 + 64], acc64);
                        acc64 = fmaf(c0.y, erow[1 * 65 + 64], acc64);
                        acc64 = fmaf(c0.z, erow[2 * 65 + 64], acc64);
                        acc64 = fmaf(c0.w, erow[3 * 65 + 64], acc64);
                    }
                }
                *(float4*)&kA[lane * KA_STR + wu * 8]     = make_float4(aK[0], aK[1], aK[2], aK[3]);
                *(float4*)&kA[lane * KA_STR + wu * 8 + 4] = make_float4(aK[4], aK[5], aK[6], aK[7]);
                *(float4*)&qA[lane * QA_STR + wu * 8]     = make_float4(aQ[0], aQ[1], aQ[2], aQ[3]);
                *(float4*)&qA[lane * QA_STR + wu * 8 + 4] = make_float4(aQ[4], aQ[5], aQ[6], aQ[7]);
                #pragma unroll
                for (int r = 0; r < 8; ++r) vsh[(ip0 + r) * 65 + lane] = aV[r];
                if (lane < 8)            k64sh[ip0 + lane] = acc64;
                else if (lane < 16)      q64sh[ip0 + (lane & 7)] = acc64;
                else if (lane < 24)      vsh[(ip0 + (lane & 7)) * 65 + 64] = acc64;
            }
            __syncthreads();

            // ---- kq partial over chunk p (global i = p*64 + 4*iq + u) ----
            for (int iq = 0; iq < 16; ++iq) {
                float4 qq = *(const float4*)&qA[lane * QA_STR + iq * 4];
                #pragma unroll
                for (int m = 0; m < 8; ++m) {
                    float4 kk = *(const float4*)&kA[(wu + 8 * m) * KA_STR + iq * 4];
                    kqa[m] = fmaf(kk.x, qq.x, kqa[m]);
                    kqa[m] = fmaf(kk.y, qq.y, kqa[m]);
                    kqa[m] = fmaf(kk.z, qq.z, kqa[m]);
                    kqa[m] = fmaf(kk.w, qq.w, kqa[m]);
                }
                if (wu == 0) {
                    float4 kc = *(const float4*)&k64sh[p * 64 + iq * 4];
                    float4 qc = *(const float4*)&q64sh[p * 64 + iq * 4];
                    kqr64acc = fmaf(kc.x, qq.x, kqr64acc);   // kq[64][t=lane]
                    kqr64acc = fmaf(kc.y, qq.y, kqr64acc);
                    kqr64acc = fmaf(kc.z, qq.z, kqr64acc);
                    kqr64acc = fmaf(kc.w, qq.w, kqr64acc);
                    float4 ks = *(const float4*)&kA[lane * KA_STR + iq * 4];
                    kq64acc = fmaf(ks.x, qc.x, kq64acc);     // kq[s=lane][64]
                    kq64acc = fmaf(ks.y, qc.y, kq64acc);
                    kq64acc = fmaf(ks.z, qc.z, kq64acc);
                    kq64acc = fmaf(ks.w, qc.w, kq64acc);
                    if (lane == 0) {
                        corner = fmaf(kc.x, qc.x, corner);   // kq[64][64]
                        corner = fmaf(kc.y, qc.y, corner);
                        corner = fmaf(kc.z, qc.z, corner);
                        corner = fmaf(kc.w, qc.w, corner);
                    }
                }
            }
            if (p == 1 && wu == 0) {
                kq64sh[lane] = kq64acc;
                if (lane == 0) kq64sh[64] = corner;
            }
            __syncthreads();
        }

        // ---- softmax in registers (same butterfly DAG) + fused att ----
        float smv[9], sm64v[9];
        #pragma unroll
        for (int m = 0; m < 9; ++m) { smv[m] = 0.f; sm64v[m] = 0.f; }
        #pragma unroll
        for (int m = 0; m < 9; ++m) {
            if (m < 8 || wu == 0) {
                int s = (m == 8) ? 64 : (wu + 8 * m);
                float lg   = (m == 8) ? kqr64acc : kqa[m];
                float l64v = (lane == 0) ? kq64sh[s] : -3.0e38f;
                float mm = fmaxf(lg, l64v);
                #pragma unroll
                for (int off = 32; off >= 1; off >>= 1) mm = fmaxf(mm, __shfl_xor(mm, off));
                float e   = expf(lg - mm);
                float e64 = (lane == 0) ? expf(l64v - mm) : 0.f;
                float zs = e + e64;
                #pragma unroll
                for (int off = 32; off >= 1; off >>= 1) zs += __shfl_xor(zs, off);
                float inv = 1.0f / zs;
                smv[m] = e * inv;
                sm64v[m] = e64 * inv;
            }
        }
        // att[s][i] = sum_t sm[s][t]*v[i][t], strict t-ascending (exact chain)
        {
            float aa0[9], aa1[9];
            #pragma unroll
            for (int m = 0; m < 9; ++m) { aa0[m] = 0.f; aa1[m] = 0.f; }
            const float* vr0 = &vsh[lane * 65];
            const float* vr1 = &vsh[(lane + 64) * 65];
            for (int t = 0; t < 64; ++t) {
                float v0 = vr0[t], v1 = vr1[t];
                #pragma unroll
                for (int m = 0; m < 9; ++m) {
                    if (m < 8 || wu == 0) {
                        float smt = __shfl(smv[m], t);
                        aa0[m] = fmaf(smt, v0, aa0[m]);
                        aa1[m] = fmaf(smt, v1, aa1[m]);
                    }
                }
            }
            float v0e = vr0[64], v1e = vr1[64];
            #pragma unroll
            for (int m = 0; m < 9; ++m) {
                if (m < 8 || wu == 0) {
                    float smt = __shfl(sm64v[m], 0);
                    aa0[m] = fmaf(smt, v0e, aa0[m]);
                    aa1[m] = fmaf(smt, v1e, aa1[m]);
                    int s = (m == 8) ? 64 : (wu + 8 * m);
                    R1[s * 128 + lane]      = aa0[m];
                    R1[s * 128 + lane + 64] = aa1[m];
                }
            }
        }
        __syncthreads();

        // stash a=0's att row 64 (R1 row-64 region is overwritten by a=1's qA)
        if (a == 0 && tid < 128) attr[tid] = R1[64 * 128 + tid];

        // ---- pre1[s][h] += sum_i att[s][i]*l1a[i][h]  (exact i-ascending) ----
        {
            const float* l1a = l1 + a * 16384;
            for (int i0b = 0; i0b < 128; i0b += 4) {
                float4 av0 = *(const float4*)&R1[(sb +  0) * 128 + i0b];
                float4 av1 = *(const float4*)&R1[(sb + 16) * 128 + i0b];
                float4 av2 = *(const float4*)&R1[(sb + 32) * 128 + i0b];
                float4 av3 = *(const float4*)&R1[(sb + 48) * 128 + i0b];
                float a0[4] = { av0.x, av0.y, av0.z, av0.w };
                float a1[4] = { av1.x, av1.y, av1.z, av1.w };
                float a2[4] = { av2.x, av2.y, av2.z, av2.w };
                float a3[4] = { av3.x, av3.y, av3.z, av3.w };
                #pragma unroll
                for (int r = 0; r < 4; ++r) {
                    float4 lv = *(const float4*)&l1a[(i0b + r) * 128 + h4];
                    acc1[0].x = fmaf(a0[r], lv.x, acc1[0].x);
                    acc1[0].y = fmaf(a0[r], lv.y, acc1[0].y);
                    acc1[0].z = fmaf(a0[r], lv.z, acc1[0].z);
                    acc1[0].w = fmaf(a0[r], lv.w, acc1[0].w);
                    acc1[1].x = fmaf(a1[r], lv.x, acc1[1].x);
                    acc1[1].y = fmaf(a1[r], lv.y, acc1[1].y);
                    acc1[1].z = fmaf(a1[r], lv.z, acc1[1].z);
                    acc1[1].w = fmaf(a1[r], lv.w, acc1[1].w);
                    acc1[2].x = fmaf(a2[r], lv.x, acc1[2].x);
                    acc1[2].y = fmaf(a2[r], lv.y, acc1[2].y);
                    acc1[2].z = fmaf(a2[r], lv.z, acc1[2].z);
                    acc1[2].w = fmaf(a2[r], lv.w, acc1[2].w);
                    acc1[3].x = fmaf(a3[r], lv.x, acc1[3].x);
                    acc1[3].y = fmaf(a3[r], lv.y, acc1[3].y);
                    acc1[3].z = fmaf(a3[r], lv.z, acc1[3].z);
                    acc1[3].w = fmaf(a3[r], lv.w, acc1[3].w);
                }
            }
        }
        __syncthreads();
    }

    // ---- row-64 pre1 (exact a0-then-a1 i-ascending chain per h) + y2 writes ----
    if (tid < 128) {
        const float* l1a0 = l1;
        const float* l1a1 = l1 + 16384;
        float acc = 0.f;
        for (int i = 0; i < 128; ++i) acc = fmaf(attr[i],        l1a0[i * 128 + tid], acc);
        for (int i = 0; i < 128; ++i) acc = fmaf(R1[64*128 + i], l1a1[i * 128 + tid], acc);
        vsh[YQ(64, tid >> 2) + (tid & 3)] = tanhf(acc);   // y2 row 64 (v dead)
    }
    // y2 rows 0..63 (YQ swizzle into vsh)
    #pragma unroll
    for (int si = 0; si < 4; ++si) {
        int s = sb + 16 * si;
        float4 tq;
        tq.x = tanhf(acc1[si].x);
        tq.y = tanhf(acc1[si].y);
        tq.z = tanhf(acc1[si].z);
        tq.w = tanhf(acc1[si].w);
        *(float4*)&vsh[YQ(s, h4 >> 2)] = tq;
    }
    __syncthreads();

    // =================== stage 2 ===================
    float pre2 = 0.f;   // valid tid < 128
    for (int a2 = 0; a2 < 2; ++a2) {
        const float* wk2 = a2 ? wk22 : wk21;
        const float* wq2 = a2 ? wq22 : wq21;
        const float* wv2 = a2 ? wv22 : wv21;

        float kq2acc = 0.f, corner2 = 0.f;

        for (int p = 0; p < 2; ++p) {
            const int ip0 = p * 64 + wu * 8;
            // ---- Q projection only (+ col-64 side chains: q2, k2) ----
            float aQ[8];
            #pragma unroll
            for (int r = 0; r < 8; ++r) aQ[r] = 0.f;
            float acc64 = 0.f;       // lane<8: q2col64   8..15: k2col64
            {
                const int ch = lane >> 3;
                const float* Wc = (ch == 0) ? wq2 : wk2;
                const float* wcrow = Wc + (ip0 + (lane & 7)) * 128;
                for (int jq = 0; jq < 32; ++jq) {
                    float4 yq = *(const float4*)&vsh[YQ(lane, jq)];
                    float yv[4] = { yq.x, yq.y, yq.z, yq.w };
                    #pragma unroll
                    for (int r = 0; r < 8; ++r) {
                        const float* wqr = wq2 + (ip0 + r) * 128 + jq * 4;
                        #pragma unroll
                        for (int u = 0; u < 4; ++u)
                            aQ[r] = fmaf(wqr[u], yv[u], aQ[r]);
                    }
                    if (lane < 16) {
                        float4 zq = *(const float4*)&vsh[YQ(64, jq)];
                        float4 c0 = *(const float4*)&wcrow[jq * 4];
                        acc64 = fmaf(c0.x, zq.x, acc64);
                        acc64 = fmaf(c0.y, zq.y, acc64);
                        acc64 = fmaf(c0.z, zq.z, acc64);
                        acc64 = fmaf(c0.w, zq.w, acc64);
                    }
                }
                *(float4*)&qA[lane * QA_STR + wu * 8]     = make_float4(aQ[0], aQ[1], aQ[2], aQ[3]);
                *(float4*)&qA[lane * QA_STR + wu * 8 + 4] = make_float4(aQ[4], aQ[5], aQ[6], aQ[7]);
                if (lane < 8)            q64sh[ip0 + lane] = acc64;
                else if (lane < 16)      k64sh[ip0 + (lane & 7)] = acc64;
            }
            __syncthreads();

            // kq2[64][t] partial (exact i-ascending), wave 0 only
            if (wu == 0) {
                for (int iq = 0; iq < 16; ++iq) {
                    float4 qq = *(const float4*)&qA[lane * QA_STR + iq * 4];
                    float4 kk = *(const float4*)&k64sh[p * 64 + iq * 4];
                    kq2acc = fmaf(kk.x, qq.x, kq2acc);
                    kq2acc = fmaf(kk.y, qq.y, kq2acc);
                    kq2acc = fmaf(kk.z, qq.z, kq2acc);
                    kq2acc = fmaf(kk.w, qq.w, kq2acc);
                    if (lane == 0) {
                        float4 qz = *(const float4*)&q64sh[p * 64 + iq * 4];
                        corner2 = fmaf(kk.x, qz.x, corner2);
                        corner2 = fmaf(kk.y, qz.y, corner2);
                        corner2 = fmaf(kk.z, qz.z, corner2);
                        corner2 = fmaf(kk.w, qz.w, corner2);
                    }
                }
            }
            __syncthreads();
        }

        // softmax2 on wave 0 (same butterfly DAG), publish to smr
        if (wu == 0) {
            float lg   = kq2acc;
            float l64v = (lane == 0) ? corner2 : -3.0e38f;
            float mm = fmaxf(lg, l64v);
            #pragma unroll
            for (int off = 32; off >= 1; off >>= 1) mm = fmaxf(mm, __shfl_xor(mm, off));
            float e   = expf(lg - mm);
            float e64 = (lane == 0) ? expf(l64v - mm) : 0.f;
            float zs = e + e64;
            #pragma unroll
            for (int off = 32; off >= 1; off >>= 1) zs += __shfl_xor(zs, off);
            float inv = 1.0f / zs;
            smr[lane] = e * inv;
            if (lane == 0) smr[64] = e64 * inv;
        }
        __syncthreads();

        // u[h] = sum_t y2[h][t]*sm2[t]  (post-final-softmax; k64sh dead -> holds u)
        if (tid < 128) {
            float uacc = 0.f;
            for (int t = 0; t <= 64; ++t)
                uacc = fmaf(smr[t], vsh[YQ(t, tid >> 2) + (tid & 3)], uacc);
            k64sh[tid] = uacc;
        }
        __syncthreads();

        // att2[i] = sum_h wv2[i][h]*u[h]  (replaces the whole V projection)
        if (tid < 128) {
            const float* wvrow = wv2 + tid * 128;
            float acc = 0.f;
            for (int h0 = 0; h0 < 128; h0 += 4) {
                float4 wq4 = *(const float4*)&wvrow[h0];
                acc = fmaf(wq4.x, k64sh[h0 + 0], acc);
                acc = fmaf(wq4.y, k64sh[h0 + 1], acc);
                acc = fmaf(wq4.z, k64sh[h0 + 2], acc);
                acc = fmaf(wq4.w, k64sh[h0 + 3], acc);
            }
            attr[tid] = acc;
        }
        __syncthreads();

        // pre2 split-K (post-softmax)
        {
            const int hh = tid & 127, cc = tid >> 7;   // cc 0..3
            const float* l2a = l2 + a2 * 16384;
            float pp = 0.f;
            #pragma unroll
            for (int g = 0; g < 8; ++g) {
                int i = cc * 32 + 4 * g;
                float4 av = *(const float4*)&attr[i];
                pp = fmaf(av.x, l2a[(i + 0) * 128 + hh], pp);
                pp = fmaf(av.y, l2a[(i + 1) * 128 + hh], pp);
                pp = fmaf(av.z, l2a[(i + 2) * 128 + hh], pp);
                pp = fmaf(av.w, l2a[(i + 3) * 128 + hh], pp);
            }
            R1[cc * 128 + hh] = pp;
        }
        __syncthreads();
        if (tid < 128) {
            float red = R1[tid];
            #pragma unroll
            for (int c = 1; c < 4; ++c) red += R1[c * 128 + tid];
            pre2 += red;
        }
        __syncthreads();
    }

    if (tid < 128) y4sh[tid] = tanhf(pre2);
    __syncthreads();

    // t3[o] = sum_h y4[h]*L3[h][o]  (split-K, post-softmax)
    {
        const int oo = tid & 63, cc = tid >> 6;   // cc 0..7
        float pp = 0.f;
        #pragma unroll
        for (int u = 0; u < 16; ++u) {
            int h = cc * 16 + u;
            pp = fmaf(y4sh[h], L3[h * 64 + oo], pp);
        }
        R1[cc * 64 + oo] = pp;
    }
    __syncthreads();
    if (tid < 64) {
        float t3 = R1[tid];
        #pragma unroll
        for (int c = 1; c < 8; ++c) t3 += R1[c * 64 + tid];
        float y5 = tanhf(t3);
        float sc = y5 * L4[tid];
        #pragma unroll
        for (int off = 32; off >= 1; off >>= 1) sc += __shfl_xor(sc, off);
        if (tid == 0) out[b] = sc;
    }
}

extern "C" void kernel_launch(void* const* d_in, const int* in_sizes, int n_in,
                              void* d_out, int out_size, void* d_ws, size_t ws_size,
                              hipStream_t stream) {
    const float* in0  = (const float*)d_in[0];
    const float* emb  = (const float*)d_in[1];
    const float* wk11 = (const float*)d_in[2];
    const float* wq11 = (const float*)d_in[3];
    const float* wv11 = (const float*)d_in[4];
    const float* wk12 = (const float*)d_in[5];
    const float* wq12 = (const float*)d_in[6];
    const float* wv12 = (const float*)d_in[7];
    const float* l1   = (const float*)d_in[8];
    const float* wk21 = (const float*)d_in[9];
    const float* wq21 = (const float*)d_in[10];
    const float* wv21 = (const float*)d_in[11];
    const float* wk22 = (const float*)d_in[12];
    const float* wq22 = (const float*)d_in[13];
    const float* wv22 = (const float*)d_in[14];
    const float* l2   = (const float*)d_in[15];
    const float* l3   = (const float*)d_in[16];
    const float* l4   = (const float*)d_in[17];
    float* out = (float*)d_out;

    int B = in_sizes[0] / 64;   // 8192

    literal_kernel<<<B, 512, 0, stream>>>(in0, emb,
                                          wk11, wq11, wv11, wk12, wq12, wv12, l1,
                                          wk21, wq21, wv21, wk22, wq22, wv22, l2,
                                          l3, l4, out);
}

// Round 14
// 5398.000 us; speedup vs baseline: 4.1178x; 4.1178x over previous
//
#include <hip/hip_runtime.h>
#include <math.h>

// Round 14 = round 11 BYTE-FOR-BYTE (best, 5401 us), with amdgpu_waves_per_eu
// changed (4,8) -> (4,6). A/B series on the VGPR budget:
//   (4,8): budget 64  -> 1.7 GB spill, dur 5401 (r11)
//   none:  budget 128 -> 31.5 GB scratch blowup + 1 block/CU, dur 22227 (r13)
//   (4,6): budget ~84 -> the untested middle: covers the ~75-reg hot-phase
//          peaks (kills the small spills) while staying below the 128-mode
//          allocator blowup; 84 VGPR still allows 4 waves/SIMD = 2 blocks/CU.
// Single-variable change; kernel body identical to r11.

#define YQ(s, q) ((s) * 128 + 4 * ((q) ^ ((s) & 7)))
#define KA_STR 68
#define QA_STR 72
#define QA_BASE 4420   // floats; byte offset 17680 (16B aligned)

__global__
__attribute__((amdgpu_flat_work_group_size(512, 512)))
__attribute__((amdgpu_waves_per_eu(4, 6)))
void literal_kernel(const float* __restrict__ in0,
                    const float* __restrict__ emb,
                    const float* __restrict__ wk11, const float* __restrict__ wq11,
                    const float* __restrict__ wv11,
                    const float* __restrict__ wk12, const float* __restrict__ wq12,
                    const float* __restrict__ wv12,
                    const float* __restrict__ l1,
                    const float* __restrict__ wk21, const float* __restrict__ wq21,
                    const float* __restrict__ wv21,
                    const float* __restrict__ wk22, const float* __restrict__ wq22,
                    const float* __restrict__ wv22,
                    const float* __restrict__ l2,
                    const float* __restrict__ L3, const float* __restrict__ L4,
                    float* __restrict__ out)
{
    __shared__ __align__(16) float vsh[8320];   // v[i][t] stride 65; later y2 (YQ)
    __shared__ __align__(16) float R1[9028];    // kA[65][68]@0, qA[64][72]@4420;
                                                // att[s*128+i] overlay; scratch
    __shared__ __align__(16) float k64sh[128];  // k[:,64] / k2[:,64]; then u[h]
    __shared__ __align__(16) float q64sh[128];  // q[:,64] / q2[:,64]
    __shared__ float kq64sh[68];
    __shared__ __align__(16) float smr[68];
    __shared__ __align__(16) float attr[128];   // st1: att_a0[64][.] stash; st2: att2
    __shared__ float y4sh[128];

    const int tid  = threadIdx.x;
    const int lane = tid & 63;
    const int wu   = __builtin_amdgcn_readfirstlane(tid >> 6);   // wave 0..7
    const long b   = blockIdx.x;
    const float xr = in0[b * 64 + lane];

    float* kA = R1;
    float* qA = R1 + QA_BASE;

    const int h4 = (tid & 31) * 4;
    const int sb = tid >> 5;          // 0..15
    float4 acc1[4];
    #pragma unroll
    for (int si = 0; si < 4; ++si) acc1[si] = make_float4(0.f, 0.f, 0.f, 0.f);

    // =================== stage 1 ===================
    for (int a = 0; a < 2; ++a) {
        const float* wk = a ? wk12 : wk11;
        const float* wq = a ? wq12 : wq11;
        const float* wv = a ? wv12 : wv11;

        float kqa[8];
        #pragma unroll
        for (int m = 0; m < 8; ++m) kqa[m] = 0.f;
        float kq64acc = 0.f, kqr64acc = 0.f, corner = 0.f;   // wave-0 extras

        for (int p = 0; p < 2; ++p) {
            const int ip0 = p * 64 + wu * 8;
            // ---- projection pass p: rows ip0..ip0+7, lanes = column s/t ----
            float aK[8], aQ[8], aV[8];
            #pragma unroll
            for (int r = 0; r < 8; ++r) { aK[r] = aQ[r] = aV[r] = 0.f; }
            float acc64 = 0.f;                     // lane<8:K64 8..15:Q64 16..23:V64
            {
                const int ch = lane >> 3;
                const float* Wc = (ch == 0) ? wk : ((ch == 1) ? wq : wv);
                const float* wcrow = Wc + (ip0 + (lane & 7)) * 128;
                for (int jq = 0; jq < 32; ++jq) {
                    const float* erow = emb + (jq * 4) * 65;
                    float yv[4];
                    #pragma unroll
                    for (int u = 0; u < 4; ++u) yv[u] = erow[u * 65 + lane] * xr;
                    #pragma unroll
                    for (int r = 0; r < 8; ++r) {
                        const float* wkr = wk + (ip0 + r) * 128 + jq * 4;
                        const float* wqr = wq + (ip0 + r) * 128 + jq * 4;
                        const float* wvr = wv + (ip0 + r) * 128 + jq * 4;
                        #pragma unroll
                        for (int u = 0; u < 4; ++u) {
                            aK[r] = fmaf(wkr[u], yv[u], aK[r]);
                            aQ[r] = fmaf(wqr[u], yv[u], aQ[r]);
                            aV[r] = fmaf(wvr[u], yv[u], aV[r]);
                        }
                    }
                    if (lane < 24) {
                        float4 c0 = *(const float4*)&wcrow[jq * 4];
                        acc64 = fmaf(c0.x, erow[0 * 65 + 64], acc64);
                        acc64 = fmaf(c0.y, erow[1 * 65 + 64], acc64);
                        acc64 = fmaf(c0.z, erow[2 * 65 + 64], acc64);
                        acc64 = fmaf(c0.w, erow[3 * 65 + 64], acc64);
                    }
                }
                *(float4*)&kA[lane * KA_STR + wu * 8]     = make_float4(aK[0], aK[1], aK[2], aK[3]);
                *(float4*)&kA[lane * KA_STR + wu * 8 + 4] = make_float4(aK[4], aK[5], aK[6], aK[7]);
                *(float4*)&qA[lane * QA_STR + wu * 8]     = make_float4(aQ[0], aQ[1], aQ[2], aQ[3]);
                *(float4*)&qA[lane * QA_STR + wu * 8 + 4] = make_float4(aQ[4], aQ[5], aQ[6], aQ[7]);
                #pragma unroll
                for (int r = 0; r < 8; ++r) vsh[(ip0 + r) * 65 + lane] = aV[r];
                if (lane < 8)            k64sh[ip0 + lane] = acc64;
                else if (lane < 16)      q64sh[ip0 + (lane & 7)] = acc64;
                else if (lane < 24)      vsh[(ip0 + (lane & 7)) * 65 + 64] = acc64;
            }
            __syncthreads();

            // ---- kq partial over chunk p (global i = p*64 + 4*iq + u) ----
            for (int iq = 0; iq < 16; ++iq) {
                float4 qq = *(const float4*)&qA[lane * QA_STR + iq * 4];
                #pragma unroll
                for (int m = 0; m < 8; ++m) {
                    float4 kk = *(const float4*)&kA[(wu + 8 * m) * KA_STR + iq * 4];
                    kqa[m] = fmaf(kk.x, qq.x, kqa[m]);
                    kqa[m] = fmaf(kk.y, qq.y, kqa[m]);
                    kqa[m] = fmaf(kk.z, qq.z, kqa[m]);
                    kqa[m] = fmaf(kk.w, qq.w, kqa[m]);
                }
                if (wu == 0) {
                    float4 kc = *(const float4*)&k64sh[p * 64 + iq * 4];
                    float4 qc = *(const float4*)&q64sh[p * 64 + iq * 4];
                    kqr64acc = fmaf(kc.x, qq.x, kqr64acc);   // kq[64][t=lane]
                    kqr64acc = fmaf(kc.y, qq.y, kqr64acc);
                    kqr64acc = fmaf(kc.z, qq.z, kqr64acc);
                    kqr64acc = fmaf(kc.w, qq.w, kqr64acc);
                    float4 ks = *(const float4*)&kA[lane * KA_STR + iq * 4];
                    kq64acc = fmaf(ks.x, qc.x, kq64acc);     // kq[s=lane][64]
                    kq64acc = fmaf(ks.y, qc.y, kq64acc);
                    kq64acc = fmaf(ks.z, qc.z, kq64acc);
                    kq64acc = fmaf(ks.w, qc.w, kq64acc);
                    if (lane == 0) {
                        corner = fmaf(kc.x, qc.x, corner);   // kq[64][64]
                        corner = fmaf(kc.y, qc.y, corner);
                        corner = fmaf(kc.z, qc.z, corner);
                        corner = fmaf(kc.w, qc.w, corner);
                    }
                }
            }
            if (p == 1 && wu == 0) {
                kq64sh[lane] = kq64acc;
                if (lane == 0) kq64sh[64] = corner;
            }
            __syncthreads();
        }

        // ---- softmax in registers (same butterfly DAG) + fused att ----
        float smv[9], sm64v[9];
        #pragma unroll
        for (int m = 0; m < 9; ++m) { smv[m] = 0.f; sm64v[m] = 0.f; }
        #pragma unroll
        for (int m = 0; m < 9; ++m) {
            if (m < 8 || wu == 0) {
                int s = (m == 8) ? 64 : (wu + 8 * m);
                float lg   = (m == 8) ? kqr64acc : kqa[m];
                float l64v = (lane == 0) ? kq64sh[s] : -3.0e38f;
                float mm = fmaxf(lg, l64v);
                #pragma unroll
                for (int off = 32; off >= 1; off >>= 1) mm = fmaxf(mm, __shfl_xor(mm, off));
                float e   = expf(lg - mm);
                float e64 = (lane == 0) ? expf(l64v - mm) : 0.f;
                float zs = e + e64;
                #pragma unroll
                for (int off = 32; off >= 1; off >>= 1) zs += __shfl_xor(zs, off);
                float inv = 1.0f / zs;
                smv[m] = e * inv;
                sm64v[m] = e64 * inv;
            }
        }
        // att[s][i] = sum_t sm[s][t]*v[i][t], strict t-ascending (exact chain)
        {
            float aa0[9], aa1[9];
            #pragma unroll
            for (int m = 0; m < 9; ++m) { aa0[m] = 0.f; aa1[m] = 0.f; }
            const float* vr0 = &vsh[lane * 65];
            const float* vr1 = &vsh[(lane + 64) * 65];
            for (int t = 0; t < 64; ++t) {
                float v0 = vr0[t], v1 = vr1[t];
                #pragma unroll
                for (int m = 0; m < 9; ++m) {
                    if (m < 8 || wu == 0) {
                        float smt = __shfl(smv[m], t);
                        aa0[m] = fmaf(smt, v0, aa0[m]);
                        aa1[m] = fmaf(smt, v1, aa1[m]);
                    }
                }
            }
            float v0e = vr0[64], v1e = vr1[64];
            #pragma unroll
            for (int m = 0; m < 9; ++m) {
                if (m < 8 || wu == 0) {
                    float smt = __shfl(sm64v[m], 0);
                    aa0[m] = fmaf(smt, v0e, aa0[m]);
                    aa1[m] = fmaf(smt, v1e, aa1[m]);
                    int s = (m == 8) ? 64 : (wu + 8 * m);
                    R1[s * 128 + lane]      = aa0[m];
                    R1[s * 128 + lane + 64] = aa1[m];
                }
            }
        }
        __syncthreads();

        // stash a=0's att row 64 (R1 row-64 region is overwritten by a=1's qA)
        if (a == 0 && tid < 128) attr[tid] = R1[64 * 128 + tid];

        // ---- pre1[s][h] += sum_i att[s][i]*l1a[i][h]  (exact i-ascending) ----
        {
            const float* l1a = l1 + a * 16384;
            for (int i0b = 0; i0b < 128; i0b += 4) {
                float4 av0 = *(const float4*)&R1[(sb +  0) * 128 + i0b];
                float4 av1 = *(const float4*)&R1[(sb + 16) * 128 + i0b];
                float4 av2 = *(const float4*)&R1[(sb + 32) * 128 + i0b];
                float4 av3 = *(const float4*)&R1[(sb + 48) * 128 + i0b];
                float a0[4] = { av0.x, av0.y, av0.z, av0.w };
                float a1[4] = { av1.x, av1.y, av1.z, av1.w };
                float a2[4] = { av2.x, av2.y, av2.z, av2.w };
                float a3[4] = { av3.x, av3.y, av3.z, av3.w };
                #pragma unroll
                for (int r = 0; r < 4; ++r) {
                    float4 lv = *(const float4*)&l1a[(i0b + r) * 128 + h4];
                    acc1[0].x = fmaf(a0[r], lv.x, acc1[0].x);
                    acc1[0].y = fmaf(a0[r], lv.y, acc1[0].y);
                    acc1[0].z = fmaf(a0[r], lv.z, acc1[0].z);
                    acc1[0].w = fmaf(a0[r], lv.w, acc1[0].w);
                    acc1[1].x = fmaf(a1[r], lv.x, acc1[1].x);
                    acc1[1].y = fmaf(a1[r], lv.y, acc1[1].y);
                    acc1[1].z = fmaf(a1[r], lv.z, acc1[1].z);
                    acc1[1].w = fmaf(a1[r], lv.w, acc1[1].w);
                    acc1[2].x = fmaf(a2[r], lv.x, acc1[2].x);
                    acc1[2].y = fmaf(a2[r], lv.y, acc1[2].y);
                    acc1[2].z = fmaf(a2[r], lv.z, acc1[2].z);
                    acc1[2].w = fmaf(a2[r], lv.w, acc1[2].w);
                    acc1[3].x = fmaf(a3[r], lv.x, acc1[3].x);
                    acc1[3].y = fmaf(a3[r], lv.y, acc1[3].y);
                    acc1[3].z = fmaf(a3[r], lv.z, acc1[3].z);
                    acc1[3].w = fmaf(a3[r], lv.w, acc1[3].w);
                }
            }
        }
        __syncthreads();
    }

    // ---- row-64 pre1 (exact a0-then-a1 i-ascending chain per h) + y2 writes ----
    if (tid < 128) {
        const float* l1a0 = l1;
        const float* l1a1 = l1 + 16384;
        float acc = 0.f;
        for (int i = 0; i < 128; ++i) acc = fmaf(attr[i],        l1a0[i * 128 + tid], acc);
        for (int i = 0; i < 128; ++i) acc = fmaf(R1[64*128 + i], l1a1[i * 128 + tid], acc);
        vsh[YQ(64, tid >> 2) + (tid & 3)] = tanhf(acc);   // y2 row 64 (v dead)
    }
    // y2 rows 0..63 (YQ swizzle into vsh)
    #pragma unroll
    for (int si = 0; si < 4; ++si) {
        int s = sb + 16 * si;
        float4 tq;
        tq.x = tanhf(acc1[si].x);
        tq.y = tanhf(acc1[si].y);
        tq.z = tanhf(acc1[si].z);
        tq.w = tanhf(acc1[si].w);
        *(float4*)&vsh[YQ(s, h4 >> 2)] = tq;
    }
    __syncthreads();

    // =================== stage 2 ===================
    float pre2 = 0.f;   // valid tid < 128
    for (int a2 = 0; a2 < 2; ++a2) {
        const float* wk2 = a2 ? wk22 : wk21;
        const float* wq2 = a2 ? wq22 : wq21;
        const float* wv2 = a2 ? wv22 : wv21;

        float kq2acc = 0.f, corner2 = 0.f;

        for (int p = 0; p < 2; ++p) {
            const int ip0 = p * 64 + wu * 8;
            // ---- Q projection only (+ col-64 side chains: q2, k2) ----
            float aQ[8];
            #pragma unroll
            for (int r = 0; r < 8; ++r) aQ[r] = 0.f;
            float acc64 = 0.f;       // lane<8: q2col64   8..15: k2col64
            {
                const int ch = lane >> 3;
                const float* Wc = (ch == 0) ? wq2 : wk2;
                const float* wcrow = Wc + (ip0 + (lane & 7)) * 128;
                for (int jq = 0; jq < 32; ++jq) {
                    float4 yq = *(const float4*)&vsh[YQ(lane, jq)];
                    float yv[4] = { yq.x, yq.y, yq.z, yq.w };
                    #pragma unroll
                    for (int r = 0; r < 8; ++r) {
                        const float* wqr = wq2 + (ip0 + r) * 128 + jq * 4;
                        #pragma unroll
                        for (int u = 0; u < 4; ++u)
                            aQ[r] = fmaf(wqr[u], yv[u], aQ[r]);
                    }
                    if (lane < 16) {
                        float4 zq = *(const float4*)&vsh[YQ(64, jq)];
                        float4 c0 = *(const float4*)&wcrow[jq * 4];
                        acc64 = fmaf(c0.x, zq.x, acc64);
                        acc64 = fmaf(c0.y, zq.y, acc64);
                        acc64 = fmaf(c0.z, zq.z, acc64);
                        acc64 = fmaf(c0.w, zq.w, acc64);
                    }
                }
                *(float4*)&qA[lane * QA_STR + wu * 8]     = make_float4(aQ[0], aQ[1], aQ[2], aQ[3]);
                *(float4*)&qA[lane * QA_STR + wu * 8 + 4] = make_float4(aQ[4], aQ[5], aQ[6], aQ[7]);
                if (lane < 8)            q64sh[ip0 + lane] = acc64;
                else if (lane < 16)      k64sh[ip0 + (lane & 7)] = acc64;
            }
            __syncthreads();

            // kq2[64][t] partial (exact i-ascending), wave 0 only
            if (wu == 0) {
                for (int iq = 0; iq < 16; ++iq) {
                    float4 qq = *(const float4*)&qA[lane * QA_STR + iq * 4];
                    float4 kk = *(const float4*)&k64sh[p * 64 + iq * 4];
                    kq2acc = fmaf(kk.x, qq.x, kq2acc);
                    kq2acc = fmaf(kk.y, qq.y, kq2acc);
                    kq2acc = fmaf(kk.z, qq.z, kq2acc);
                    kq2acc = fmaf(kk.w, qq.w, kq2acc);
                    if (lane == 0) {
                        float4 qz = *(const float4*)&q64sh[p * 64 + iq * 4];
                        corner2 = fmaf(kk.x, qz.x, corner2);
                        corner2 = fmaf(kk.y, qz.y, corner2);
                        corner2 = fmaf(kk.z, qz.z, corner2);
                        corner2 = fmaf(kk.w, qz.w, corner2);
                    }
                }
            }
            __syncthreads();
        }

        // softmax2 on wave 0 (same butterfly DAG), publish to smr
        if (wu == 0) {
            float lg   = kq2acc;
            float l64v = (lane == 0) ? corner2 : -3.0e38f;
            float mm = fmaxf(lg, l64v);
            #pragma unroll
            for (int off = 32; off >= 1; off >>= 1) mm = fmaxf(mm, __shfl_xor(mm, off));
            float e   = expf(lg - mm);
            float e64 = (lane == 0) ? expf(l64v - mm) : 0.f;
            float zs = e + e64;
            #pragma unroll
            for (int off = 32; off >= 1; off >>= 1) zs += __shfl_xor(zs, off);
            float inv = 1.0f / zs;
            smr[lane] = e * inv;
            if (lane == 0) smr[64] = e64 * inv;
        }
        __syncthreads();

        // u[h] = sum_t y2[h][t]*sm2[t]  (post-final-softmax; k64sh dead -> holds u)
        if (tid < 128) {
            float uacc = 0.f;
            for (int t = 0; t <= 64; ++t)
                uacc = fmaf(smr[t], vsh[YQ(t, tid >> 2) + (tid & 3)], uacc);
            k64sh[tid] = uacc;
        }
        __syncthreads();

        // att2[i] = sum_h wv2[i][h]*u[h]  (replaces the whole V projection)
        if (tid < 128) {
            const float* wvrow = wv2 + tid * 128;
            float acc = 0.f;
            for (int h0 = 0; h0 < 128; h0 += 4) {
                float4 wq4 = *(const float4*)&wvrow[h0];
                acc = fmaf(wq4.x, k64sh[h0 + 0], acc);
                acc = fmaf(wq4.y, k64sh[h0 + 1], acc);
                acc = fmaf(wq4.z, k64sh[h0 + 2], acc);
                acc = fmaf(wq4.w, k64sh[h0 + 3], acc);
            }
            attr[tid] = acc;
        }
        __syncthreads();

        // pre2 split-K (post-softmax)
        {
            const int hh = tid & 127, cc = tid >> 7;   // cc 0..3
            const float* l2a = l2 + a2 * 16384;
            float pp = 0.f;
            #pragma unroll
            for (int g = 0; g < 8; ++g) {
                int i = cc * 32 + 4 * g;
                float4 av = *(const float4*)&attr[i];
                pp = fmaf(av.x, l2a[(i + 0) * 128 + hh], pp);
                pp = fmaf(av.y, l2a[(i + 1) * 128 + hh], pp);
                pp = fmaf(av.z, l2a[(i + 2) * 128 + hh], pp);
                pp = fmaf(av.w, l2a[(i + 3) * 128 + hh], pp);
            }
            R1[cc * 128 + hh] = pp;
        }
        __syncthreads();
        if (tid < 128) {
            float red = R1[tid];
            #pragma unroll
            for (int c = 1; c < 4; ++c) red += R1[c * 128 + tid];
            pre2 += red;
        }
        __syncthreads();
    }

    if (tid < 128) y4sh[tid] = tanhf(pre2);
    __syncthreads();

    // t3[o] = sum_h y4[h]*L3[h][o]  (split-K, post-softmax)
    {
        const int oo = tid & 63, cc = tid >> 6;   // cc 0..7
        float pp = 0.f;
        #pragma unroll
        for (int u = 0; u < 16; ++u) {
            int h = cc * 16 + u;
            pp = fmaf(y4sh[h], L3[h * 64 + oo], pp);
        }
        R1[cc * 64 + oo] = pp;
    }
    __syncthreads();
    if (tid < 64) {
        float t3 = R1[tid];
        #pragma unroll
        for (int c = 1; c < 8; ++c) t3 += R1[c * 64 + tid];
        float y5 = tanhf(t3);
        float sc = y5 * L4[tid];
        #pragma unroll
        for (int off = 32; off >= 1; off >>= 1) sc += __shfl_xor(sc, off);
        if (tid == 0) out[b] = sc;
    }
}

extern "C" void kernel_launch(void* const* d_in, const int* in_sizes, int n_in,
                              void* d_out, int out_size, void* d_ws, size_t ws_size,
                              hipStream_t stream) {
    const float* in0  = (const float*)d_in[0];
    const float* emb  = (const float*)d_in[1];
    const float* wk11 = (const float*)d_in[2];
    const float* wq11 = (const float*)d_in[3];
    const float* wv11 = (const float*)d_in[4];
    const float* wk12 = (const float*)d_in[5];
    const float* wq12 = (const float*)d_in[6];
    const float* wv12 = (const float*)d_in[7];
    const float* l1   = (const float*)d_in[8];
    const float* wk21 = (const float*)d_in[9];
    const float* wq21 = (const float*)d_in[10];
    const float* wv21 = (const float*)d_in[11];
    const float* wk22 = (const float*)d_in[12];
    const float* wq22 = (const float*)d_in[13];
    const float* wv22 = (const float*)d_in[14];
    const float* l2   = (const float*)d_in[15];
    const float* l3   = (const float*)d_in[16];
    const float* l4   = (const float*)d_in[17];
    float* out = (float*)d_out;

    int B = in_sizes[0] / 64;   // 8192

    literal_kernel<<<B, 512, 0, stream>>>(in0, emb,
                                          wk11, wq11, wv11, wk12, wq12, wv12, l1,
                                          wk21, wq21, wv21, wk22, wq22, wv22, l2,
                                          l3, l4, out);
}